// Round 2
// baseline (267.171 us; speedup 1.0000x reference)
//
#include <hip/hip_runtime.h>
#include <limits.h>

#define S_U 256
#define N_IMP 128
#define OUT_STRIDE (4 + N_IMP)
#define TRUNC 0.015625f   // 2/512*4
#define WPB 4             // waves (= rays) per 256-thread block
#define INV127 (1.0f / 127.0f)

// ---------------- DPP cross-lane helpers (no LDS/ds_bpermute) ----------------
// update_dpp: invalid/masked source lanes return `old` -> identity-fill.
template<int CTRL, int RM, int BM>
__device__ __forceinline__ int dpp_i(int old_, int x) {
    return __builtin_amdgcn_update_dpp(old_, x, CTRL, RM, BM, false);
}
template<int CTRL, int RM, int BM>
__device__ __forceinline__ float dpp_f(float old_, float x) {
    return __int_as_float(__builtin_amdgcn_update_dpp(
        __float_as_int(old_), __float_as_int(x), CTRL, RM, BM, false));
}
__device__ __forceinline__ float readlane_f(float x, int l) {
    return __int_as_float(__builtin_amdgcn_readlane(__float_as_int(x), l));
}

// Full-wave inclusive scans (lane63 ends with the total -> also the reductions).
// ctrl: 0x111..0x118 row_shr 1/2/4/8, 0x142 bcast15 (rows 1,3), 0x143 bcast31 (rows 2,3)
__device__ __forceinline__ float wscan_add(float x) {
    x += dpp_f<0x111,0xf,0xf>(0.0f, x);
    x += dpp_f<0x112,0xf,0xf>(0.0f, x);
    x += dpp_f<0x114,0xf,0xf>(0.0f, x);
    x += dpp_f<0x118,0xf,0xf>(0.0f, x);
    x += dpp_f<0x142,0xa,0xf>(0.0f, x);
    x += dpp_f<0x143,0xc,0xf>(0.0f, x);
    return x;
}
__device__ __forceinline__ float wscan_mul(float x) {
    x *= dpp_f<0x111,0xf,0xf>(1.0f, x);
    x *= dpp_f<0x112,0xf,0xf>(1.0f, x);
    x *= dpp_f<0x114,0xf,0xf>(1.0f, x);
    x *= dpp_f<0x118,0xf,0xf>(1.0f, x);
    x *= dpp_f<0x142,0xa,0xf>(1.0f, x);
    x *= dpp_f<0x143,0xc,0xf>(1.0f, x);
    return x;
}
__device__ __forceinline__ int wscan_max(int x) {   // values >= 0
    x = max(x, dpp_i<0x111,0xf,0xf>(0, x));
    x = max(x, dpp_i<0x112,0xf,0xf>(0, x));
    x = max(x, dpp_i<0x114,0xf,0xf>(0, x));
    x = max(x, dpp_i<0x118,0xf,0xf>(0, x));
    x = max(x, dpp_i<0x142,0xa,0xf>(0, x));
    x = max(x, dpp_i<0x143,0xc,0xf>(0, x));
    return x;
}
__device__ __forceinline__ int wred_min(int x) {    // result valid in lane 63
    x = min(x, dpp_i<0x111,0xf,0xf>(INT_MAX, x));
    x = min(x, dpp_i<0x112,0xf,0xf>(INT_MAX, x));
    x = min(x, dpp_i<0x114,0xf,0xf>(INT_MAX, x));
    x = min(x, dpp_i<0x118,0xf,0xf>(INT_MAX, x));
    x = min(x, dpp_i<0x142,0xa,0xf>(INT_MAX, x));
    x = min(x, dpp_i<0x143,0xc,0xf>(INT_MAX, x));
    return x;
}

// Exact jmin = min{ j in [0,128] : (float)j * INV127 >= c }  (128 == "no sample")
// Same predicate orientation as the old binary search (cdf <= u counts), so bin
// selection is numerically identical; ceil gets within +-1, fixup makes it exact.
__device__ __forceinline__ int jm_of(float c) {
    int jm = (int)ceilf(c * 127.0f);
    jm = min(max(jm, 0), 128);
    if (jm > 0 && (float)(jm - 1) * INV127 >= c) jm--;
    else if (jm < 128 && (float)jm * INV127 < c) jm++;
    return jm;
}

__global__ __launch_bounds__(256) void tsdf_render_kernel(
    const float* __restrict__ occ,
    const float* __restrict__ zvals,
    const float* __restrict__ sdf,
    const float* __restrict__ rgbs,
    float* __restrict__ out)
{
    const int lane = threadIdx.x & 63;
    const int wv   = threadIdx.x >> 6;
    const int ray  = blockIdx.x * WPB + wv;

    __shared__ __align__(16) float s_cdf [WPB][S_U];
    __shared__ __align__(16) float s_zmid[WPB][S_U];
    __shared__ __align__(16) int   s_bs  [WPB][N_IMP];   // "below" segment starts

    // ---------------- global loads issued up front (latency overlap) --------
    const float4 o4  = ((const float4*)(occ   + (size_t)ray * S_U))[lane];
    const float4 z4  = ((const float4*)(zvals + (size_t)ray * S_U))[lane];
    const float2 sd2 = ((const float2*)(sdf   + (size_t)ray * N_IMP))[lane];
    const float2* rg = (const float2*)(rgbs + (size_t)ray * (N_IMP * 3)) + lane * 3;
    const float2 p0 = rg[0];   // r0 g0
    const float2 p1 = rg[1];   // b0 r1
    const float2 p2 = rg[2];   // g1 b1

    // ---------------- coarse occupancy -> weights ---------------------------
    // exact div kept: alphas feed the CDF (bin decisions)
    float a0 = 1.0f / (1.0f + __expf(-10.0f * o4.x));
    float a1 = 1.0f / (1.0f + __expf(-10.0f * o4.y));
    float a2 = 1.0f / (1.0f + __expf(-10.0f * o4.z));
    float a3 = 1.0f / (1.0f + __expf(-10.0f * o4.w));
    float t0 = 1.0f - a0 + 1e-10f;
    float t1 = 1.0f - a1 + 1e-10f;
    float t2 = 1.0f - a2 + 1e-10f;
    float t3 = 1.0f - a3 + 1e-10f;

    float pp0 = t0, pp1 = pp0 * t1, pp2 = pp1 * t2, pp3 = pp2 * t3;
    float P = wscan_mul(pp3);                       // inclusive product scan
    float pbase = dpp_f<0x138,0xf,0xf>(1.0f, P);    // wave_shr1: exclusive, lane0=1

    float w0 = a0 * pbase;
    float w1 = a1 * pbase * pp0;
    float w2 = a2 * pbase * pp1;
    float w3 = a3 * pbase * pp2;

    // ---------------- CDF over w_u[1..254] + 1e-5 ---------------------------
    float v0 = (lane > 0)  ? w0 + 1e-5f : 0.0f;
    float v1 = w1 + 1e-5f;
    float v2 = w2 + 1e-5f;
    float v3 = (lane < 63) ? w3 + 1e-5f : 0.0f;
    float s0 = v0, s1 = s0 + v1, s2 = s1 + v2, s3 = s2 + v3;
    float S  = wscan_add(s3);                       // inclusive sum scan
    float sbase = dpp_f<0x138,0xf,0xf>(0.0f, S);    // exclusive base
    float total = readlane_f(S, 63);
    float invt = 1.0f / total;                      // exact (feeds bin decisions)

    float4 cdf4;
    cdf4.x = (sbase + s0) * invt;
    cdf4.y = (sbase + s1) * invt;
    cdf4.z = (sbase + s2) * invt;
    cdf4.w = (sbase + s3) * invt;
    *((float4*)&s_cdf[wv][lane * 4]) = cdf4;

    float znext = dpp_f<0x130,0xf,0xf>(z4.x, z4.x); // wave_shl1 (shfl_down 1), lane63 -> own
    float4 zm4;
    zm4.x = 0.5f * (z4.x + z4.y);
    zm4.y = 0.5f * (z4.y + z4.z);
    zm4.z = 0.5f * (z4.z + z4.w);
    zm4.w = 0.5f * (z4.w + znext);                  // index 255: only hit in degenerate t~0 case
    *((float4*)&s_zmid[wv][lane * 4]) = zm4;

    // init segment-start array
    *((int2*)&s_bs[wv][lane * 2]) = make_int2(0, 0);

    __builtin_amdgcn_wave_barrier();   // LDS is in-order per wave; pin compiler order

    // ---------------- analytic CDF inversion (replaces binary search) ------
    // entry i = 4*lane+k covers samples j in [jm_i, jm_{i+1}); keep only the
    // LAST entry per jm (strictly increasing after dedupe -> conflict-free writes)
    int jm0 = jm_of(cdf4.x);
    int jm1 = jm_of(cdf4.y);
    int jm2 = jm_of(cdf4.z);
    int jm3 = jm_of(cdf4.w);
    if (lane == 63) jm3 = 128;                       // entry 255 doesn't exist; cap entry 254
    int jmn = dpp_i<0x130,0xf,0xf>(128, jm0);        // next lane's jm0, lane63 -> sentinel

    int ib = lane * 4;
    if (jm0 < jm1) s_bs[wv][jm0] = ib;
    if (jm1 < jm2) s_bs[wv][jm1] = ib + 1;
    if (jm2 < jm3) s_bs[wv][jm2] = ib + 2;
    if (jm3 < jmn) s_bs[wv][jm3] = ib + 3;

    __builtin_amdgcn_wave_barrier();

    // fill: below[j] = max segment-start index at position <= j  (DPP max-scan)
    int2 bse = *((const int2*)&s_bs[wv][lane * 2]);
    int H  = wscan_max(max(bse.x, bse.y));           // inclusive through sample 2*lane+1
    int Hp = dpp_i<0x138,0xf,0xf>(0, H);             // through sample 2*lane-1
    int b0 = max(Hp, bse.x);                         // below for sample 2*lane
    int b1 = H;                                      // below for sample 2*lane+1

    // ---------------- gather + interpolate (single-level LDS reads) ---------
    const float* cdfp = s_cdf[wv];
    const float* zmp  = s_zmid[wv];
    float u0 = (float)(2 * lane)     * INV127;
    float u1 = (float)(2 * lane + 1) * INV127;

    float cb0 = cdfp[b0], ca0 = cdfp[b0 + 1];
    float zb0 = zmp[b0],  za0 = zmp[b0 + 1];
    float cb1 = cdfp[b1], ca1 = cdfp[b1 + 1];
    float zb1 = zmp[b1],  za1 = zmp[b1 + 1];

    float d0 = ca0 - cb0; d0 = (d0 < 1e-5f) ? 1.0f : d0;
    float d1 = ca1 - cb1; d1 = (d1 < 1e-5f) ? 1.0f : d1;
    float tt0 = (u0 - cb0) * __builtin_amdgcn_rcpf(d0);   // rcp(1.0)==1.0 exactly
    float tt1 = (u1 - cb1) * __builtin_amdgcn_rcpf(d1);
    float zs0 = zb0 + tt0 * (za0 - zb0);
    float zs1 = zb1 + tt1 * (za1 - zb1);

    // ---------------- first zero-crossing of sdf ----------------------------
    float sn = dpp_f<0x130,0xf,0xf>(sd2.x, sd2.x);   // sdf[2*lane+2]; lane63 guarded
    int c = INT_MAX;
    if (sd2.x * sd2.y < 0.0f)                  c = 2 * lane;
    else if (lane < 63 && sd2.y * sn < 0.0f)   c = 2 * lane + 1;
    c = wred_min(c);
    int cis = __builtin_amdgcn_readlane(c, 63);
    cis = (cis == INT_MAX) ? 0 : cis;
    float zca = readlane_f(zs0, cis >> 1);
    float zcb = readlane_f(zs1, cis >> 1);
    float z_min = (cis & 1) ? zcb : zca;

    // ---------------- TSDF alpha + truncation mask --------------------------
    float x0 = sd2.x * (1.0f / TRUNC);
    float x1 = sd2.y * (1.0f / TRUNC);
    float al0 = __builtin_amdgcn_rcpf(2.0f + __expf(x0) + __expf(-x0));
    float al1 = __builtin_amdgcn_rcpf(2.0f + __expf(x1) + __expf(-x1));
    float zlim = z_min + TRUNC;
    if (!(zs0 < zlim)) al0 = 0.0f;
    if (!(zs1 < zlim)) al1 = 0.0f;

    float At = wscan_add(al0 + al1);
    float asum = readlane_f(At, 63);
    float inv_s = __builtin_amdgcn_rcpf(asum + 1e-8f);
    float g0 = al0 * inv_s;
    float g1 = al1 * inv_s;

    // ---------------- composite (lane63 holds the totals) -------------------
    float rr = wscan_add(g0 * p0.x + g1 * p1.y);
    float gg = wscan_add(g0 * p0.y + g1 * p2.x);
    float bb = wscan_add(g0 * p1.x + g1 * p2.y);
    float dd = wscan_add(g0 * zs0  + g1 * zs1);

    float* ob = out + (size_t)ray * OUT_STRIDE;
    ((float2*)(ob + 4))[lane] = make_float2(g0, g1);
    if (lane == 63) {
        ob[0] = fminf(fmaxf(rr, 0.0f), 1.0f);
        ob[1] = fminf(fmaxf(gg, 0.0f), 1.0f);
        ob[2] = fminf(fmaxf(bb, 0.0f), 1.0f);
        ob[3] = dd;
    }
}

extern "C" void kernel_launch(void* const* d_in, const int* in_sizes, int n_in,
                              void* d_out, int out_size, void* d_ws, size_t ws_size,
                              hipStream_t stream) {
    const float* occ  = (const float*)d_in[0];
    const float* z    = (const float*)d_in[1];
    const float* sdf  = (const float*)d_in[2];
    const float* rgbs = (const float*)d_in[3];
    float* out = (float*)d_out;
    const int n_rays = in_sizes[0] / S_U;
    hipLaunchKernelGGL(tsdf_render_kernel, dim3(n_rays / WPB), dim3(256), 0, stream,
                       occ, z, sdf, rgbs, out);
}